// Round 1
// baseline (252.947 us; speedup 1.0000x reference)
//
#include <hip/hip_runtime.h>

// GradeWiseLinear: x (8,2048,128,16) f32, block-diagonal linear over last dim
// with grade dims {1,4,6,4,1}. Memory-bound: 256 MiB total traffic.
//
// d_in order: x, w0,b0, w1,b1, w2,b2, w3,b3, w4,b4
// w_g is (d,d) row-major: out[o] = b[o] + sum_i x[lo+i] * w[o*d + i]

__global__ __launch_bounds__(256) void GradeWiseLinear_kernel(
    const float* __restrict__ x,
    const float* __restrict__ w0, const float* __restrict__ b0,
    const float* __restrict__ w1, const float* __restrict__ b1,
    const float* __restrict__ w2, const float* __restrict__ b2,
    const float* __restrict__ w3, const float* __restrict__ b3,
    const float* __restrict__ w4, const float* __restrict__ b4,
    float* __restrict__ out, int n_rows)
{
    // Packed LDS layout:
    // [0]      w0 (1)
    // [1..16]  w1 (4x4)
    // [17..52] w2 (6x6)
    // [53..68] w3 (4x4)
    // [69]     w4 (1)
    // [70]     b0
    // [71..74] b1
    // [75..80] b2
    // [81..84] b3
    // [85]     b4
    __shared__ float s[86];
    {
        int t = threadIdx.x;
        if (t < 86) {
            float v;
            if      (t == 0)  v = w0[0];
            else if (t < 17)  v = w1[t - 1];
            else if (t < 53)  v = w2[t - 17];
            else if (t < 69)  v = w3[t - 53];
            else if (t == 69) v = w4[0];
            else if (t == 70) v = b0[0];
            else if (t < 75)  v = b1[t - 71];
            else if (t < 81)  v = b2[t - 75];
            else if (t < 85)  v = b3[t - 81];
            else              v = b4[0];
            s[t] = v;
        }
    }
    __syncthreads();

    long r = (long)blockIdx.x * blockDim.x + threadIdx.x;
    if (r >= n_rows) return;

    const float4* xv = (const float4*)x + r * 4;
    float4 a0 = xv[0];
    float4 a1 = xv[1];
    float4 a2 = xv[2];
    float4 a3 = xv[3];
    float in[16] = {a0.x, a0.y, a0.z, a0.w,
                    a1.x, a1.y, a1.z, a1.w,
                    a2.x, a2.y, a2.z, a2.w,
                    a3.x, a3.y, a3.z, a3.w};
    float o[16];

    // grade 0: d=1, lo=0
    o[0] = s[70] + in[0] * s[0];

    // grade 1: d=4, lo=1
    #pragma unroll
    for (int oo = 0; oo < 4; ++oo) {
        float acc = s[71 + oo];
        #pragma unroll
        for (int i = 0; i < 4; ++i) acc += in[1 + i] * s[1 + oo * 4 + i];
        o[1 + oo] = acc;
    }

    // grade 2: d=6, lo=5
    #pragma unroll
    for (int oo = 0; oo < 6; ++oo) {
        float acc = s[75 + oo];
        #pragma unroll
        for (int i = 0; i < 6; ++i) acc += in[5 + i] * s[17 + oo * 6 + i];
        o[5 + oo] = acc;
    }

    // grade 3: d=4, lo=11
    #pragma unroll
    for (int oo = 0; oo < 4; ++oo) {
        float acc = s[81 + oo];
        #pragma unroll
        for (int i = 0; i < 4; ++i) acc += in[11 + i] * s[53 + oo * 4 + i];
        o[11 + oo] = acc;
    }

    // grade 4: d=1, lo=15
    o[15] = s[85] + in[15] * s[69];

    float4* ov = (float4*)out + r * 4;
    ov[0] = make_float4(o[0],  o[1],  o[2],  o[3]);
    ov[1] = make_float4(o[4],  o[5],  o[6],  o[7]);
    ov[2] = make_float4(o[8],  o[9],  o[10], o[11]);
    ov[3] = make_float4(o[12], o[13], o[14], o[15]);
}

extern "C" void kernel_launch(void* const* d_in, const int* in_sizes, int n_in,
                              void* d_out, int out_size, void* d_ws, size_t ws_size,
                              hipStream_t stream) {
    const float* x  = (const float*)d_in[0];
    const float* w0 = (const float*)d_in[1];
    const float* b0 = (const float*)d_in[2];
    const float* w1 = (const float*)d_in[3];
    const float* b1 = (const float*)d_in[4];
    const float* w2 = (const float*)d_in[5];
    const float* b2 = (const float*)d_in[6];
    const float* w3 = (const float*)d_in[7];
    const float* b3 = (const float*)d_in[8];
    const float* w4 = (const float*)d_in[9];
    const float* b4 = (const float*)d_in[10];
    float* out = (float*)d_out;

    int n_rows = in_sizes[0] / 16;  // 2,097,152
    int block = 256;
    int grid = (n_rows + block - 1) / block;  // 8192

    GradeWiseLinear_kernel<<<grid, block, 0, stream>>>(
        x, w0, b0, w1, b1, w2, b2, w3, b3, w4, b4, out, n_rows);
}

// Round 2
// 245.822 us; speedup vs baseline: 1.0290x; 1.0290x over previous
//
#include <hip/hip_runtime.h>

// GradeWiseLinear: x (8,2048,128,16) f32, block-diagonal linear over last dim,
// grade dims {1,4,6,4,1}. Memory-bound (~256 MiB traffic, ~43 us floor).
//
// R2: one float4 (quarter-row) per thread for perfect lane coalescing.
// Each lane loads its own chunk + the two neighbor chunks (coalesced,
// L1-resident) to cover the grade-2 block that straddles chunk boundaries.
//
// LDS weight layout:
// [0]      w0 (1x1)
// [1..16]  w1 (4x4 row-major)
// [17..52] w2 (6x6 row-major)
// [53..68] w3 (4x4 row-major)
// [69]     w4 (1x1)
// [70..85] biases b0|b1|b2|b3|b4

__global__ __launch_bounds__(256) void GradeWiseLinear_kernel(
    const float* __restrict__ x,
    const float* __restrict__ w0, const float* __restrict__ b0,
    const float* __restrict__ w1, const float* __restrict__ b1,
    const float* __restrict__ w2, const float* __restrict__ b2,
    const float* __restrict__ w3, const float* __restrict__ b3,
    const float* __restrict__ w4, const float* __restrict__ b4,
    float* __restrict__ out, int n4)
{
    __shared__ float s[86];
    {
        int t = threadIdx.x;
        if (t < 86) {
            float v;
            if      (t == 0)  v = w0[0];
            else if (t < 17)  v = w1[t - 1];
            else if (t < 53)  v = w2[t - 17];
            else if (t < 69)  v = w3[t - 53];
            else if (t == 69) v = w4[0];
            else if (t == 70) v = b0[0];
            else if (t < 75)  v = b1[t - 71];
            else if (t < 81)  v = b2[t - 75];
            else if (t < 85)  v = b3[t - 81];
            else              v = b4[0];
            s[t] = v;
        }
    }
    __syncthreads();

    int g = blockIdx.x * 256 + threadIdx.x;   // float4 index
    if (g >= n4) return;

    const int j = g & 3;                      // chunk-in-row (0..3)
    const float4* x4 = (const float4*)x;

    // Own chunk + neighbors. Offsets clamped so no OOB: lanes that would
    // read past the array don't use the value (j==0 never uses `up`,
    // j==3 never uses `dn`).
    float4 me = x4[g];
    float4 up = x4[g - (int)(j > 0)];
    float4 dn = x4[g + (int)(j < 3)];

    float o0, o1, o2, o3;

    if (j == 0) {
        // out0 = b0 + x0*w0 ; out1..3 = b1[0..2] + W1[0..2] . x[1..4]
        // x0..x3 = me, x4 = dn.x
        o0 = s[70] + me.x * s[0];
        o1 = s[71] + me.y * s[1] + me.z * s[2]  + me.w * s[3]  + dn.x * s[4];
        o2 = s[72] + me.y * s[5] + me.z * s[6]  + me.w * s[7]  + dn.x * s[8];
        o3 = s[73] + me.y * s[9] + me.z * s[10] + me.w * s[11] + dn.x * s[12];
    } else if (j == 1) {
        // x1..3 = up.yzw, x4..7 = me, x8..10 = dn.xyz
        // out4 = b1[3] + W1[3] . x[1..4]
        o0 = s[74] + up.y * s[13] + up.z * s[14] + up.w * s[15] + me.x * s[16];
        // out5..7 = b2[0..2] + W2[0..2] . x[5..10]
        o1 = s[75] + me.y * s[17] + me.z * s[18] + me.w * s[19]
                   + dn.x * s[20] + dn.y * s[21] + dn.z * s[22];
        o2 = s[76] + me.y * s[23] + me.z * s[24] + me.w * s[25]
                   + dn.x * s[26] + dn.y * s[27] + dn.z * s[28];
        o3 = s[77] + me.y * s[29] + me.z * s[30] + me.w * s[31]
                   + dn.x * s[32] + dn.y * s[33] + dn.z * s[34];
    } else if (j == 2) {
        // x5..7 = up.yzw, x8..11 = me, x12..14 = dn.xyz
        // out8..10 = b2[3..5] + W2[3..5] . x[5..10]
        o0 = s[78] + up.y * s[35] + up.z * s[36] + up.w * s[37]
                   + me.x * s[38] + me.y * s[39] + me.z * s[40];
        o1 = s[79] + up.y * s[41] + up.z * s[42] + up.w * s[43]
                   + me.x * s[44] + me.y * s[45] + me.z * s[46];
        o2 = s[80] + up.y * s[47] + up.z * s[48] + up.w * s[49]
                   + me.x * s[50] + me.y * s[51] + me.z * s[52];
        // out11 = b3[0] + W3[0] . x[11..14]
        o3 = s[81] + me.w * s[53] + dn.x * s[54] + dn.y * s[55] + dn.z * s[56];
    } else {
        // x11 = up.w, x12..15 = me
        // out12..14 = b3[1..3] + W3[1..3] . x[11..14]
        o0 = s[82] + up.w * s[57] + me.x * s[58] + me.y * s[59] + me.z * s[60];
        o1 = s[83] + up.w * s[61] + me.x * s[62] + me.y * s[63] + me.z * s[64];
        o2 = s[84] + up.w * s[65] + me.x * s[66] + me.y * s[67] + me.z * s[68];
        // out15 = b4 + x15*w4
        o3 = s[85] + me.w * s[69];
    }

    ((float4*)out)[g] = make_float4(o0, o1, o2, o3);
}

extern "C" void kernel_launch(void* const* d_in, const int* in_sizes, int n_in,
                              void* d_out, int out_size, void* d_ws, size_t ws_size,
                              hipStream_t stream) {
    const float* x  = (const float*)d_in[0];
    const float* w0 = (const float*)d_in[1];
    const float* b0 = (const float*)d_in[2];
    const float* w1 = (const float*)d_in[3];
    const float* b1 = (const float*)d_in[4];
    const float* w2 = (const float*)d_in[5];
    const float* b2 = (const float*)d_in[6];
    const float* w3 = (const float*)d_in[7];
    const float* b3 = (const float*)d_in[8];
    const float* w4 = (const float*)d_in[9];
    const float* b4 = (const float*)d_in[10];
    float* out = (float*)d_out;

    int n4 = in_sizes[0] / 4;               // 8,388,608 float4 chunks
    int block = 256;
    int grid = (n4 + block - 1) / block;    // 32768

    GradeWiseLinear_kernel<<<grid, block, 0, stream>>>(
        x, w0, b0, w1, b1, w2, b2, w3, b3, w4, b4, out, n4);
}